// Round 1
// baseline (199.661 us; speedup 1.0000x reference)
//
#include <hip/hip_runtime.h>
#include <math.h>

// Problem constants
#define REC_LEN 49                 // 7x7 floats per (b,z)
#define RECS_PER_BLK 256
#define STAGE_FLOATS (RECS_PER_BLK * REC_LEN)   // 12544 floats = 49 KB
#define ZC 2048
#define NB 256
#define NPOS 64                    // 4 pixels x 16 patches

// Compute the 64 patch values (k = (p1*2+p2)*16 + h*4 + w) from a 7x7 record.
// Bilinear 7->8 resize weights (jax.image.resize, normalized triangle kernel):
// edge outputs collapse to the edge input; interior uses exact sixteenths.
__device__ __forceinline__ void patchvals(const float* __restrict__ in, float* __restrict__ out) {
    const float wA[8] = {1.f, 0.1875f, 0.3125f, 0.4375f, 0.5625f, 0.6875f, 0.8125f, 1.f};
    const float wB[8] = {0.f, 0.8125f, 0.6875f, 0.5625f, 0.4375f, 0.3125f, 0.1875f, 0.f};
    const int  i0[8]  = {0, 0, 1, 2, 3, 4, 5, 6};
    const int  i1[8]  = {0, 1, 2, 3, 4, 5, 6, 6};
#pragma unroll
    for (int r = 0; r < 8; ++r) {
        float tmp[7];
#pragma unroll
        for (int c = 0; c < 7; ++c)
            tmp[c] = wA[r] * in[i0[r] * 7 + c] + wB[r] * in[i1[r] * 7 + c];
#pragma unroll
        for (int c = 0; c < 8; ++c) {
            float v = wA[c] * tmp[i0[c]] + wB[c] * tmp[i1[c]];
            int k = (((r & 1) * 2 + (c & 1)) << 4) + ((r >> 1) << 2) + (c >> 1);
            out[k] = v;   // constant index after full unroll -> stays in VGPRs
        }
    }
}

// ---------------- Kernel A: per-block partial sums over z ----------------
// Grid 2048 blocks x 256 threads; block = 256 consecutive records (one b, one z-chunk).
// Writes part[blk][2][64]: {sum, sumsq} per patch position.
extern "C" __global__ void __launch_bounds__(256)
k_stats(const float* __restrict__ x, float* __restrict__ part) {
    __shared__ float smem[16384];   // 64 KB: stage (12544 floats) then pt[256][64] (union)
    const int tid = threadIdx.x;

    // Coalesced float4 stage of the block's 50176-byte contiguous chunk (16B aligned).
    const float4* s4 = (const float4*)(x + (size_t)blockIdx.x * STAGE_FLOATS);
    float4* l4 = (float4*)smem;
    for (int i = tid; i < STAGE_FLOATS / 4; i += 256) l4[i] = s4[i];
    __syncthreads();

    // Gather my record (stride-49: odd stride -> conflict-free).
    float in[REC_LEN];
#pragma unroll
    for (int j = 0; j < REC_LEN; ++j) in[j] = smem[tid * REC_LEN + j];
    __syncthreads();   // all gathers done; smem now reusable as pt[256][64]

    float v[NPOS];
    patchvals(in, v);

    // XOR-swizzled transpose store: row=z_local, col=k^(z&31) -> both write
    // (lanes vary z, k fixed) and read (lanes vary k, z fixed) are conflict-free.
    const int sw = tid & 31;
#pragma unroll
    for (int k = 0; k < NPOS; ++k)
        smem[tid * NPOS + (k ^ sw)] = v[k];
    __syncthreads();

    // 4 groups of 64 z's each reduce one position.
    const int k = tid & 63;
    const int g = tid >> 6;
    float S = 0.f, S2 = 0.f;
#pragma unroll 16
    for (int zi = g * 64; zi < g * 64 + 64; ++zi) {
        float t = smem[zi * NPOS + (k ^ (zi & 31))];
        S += t; S2 += t * t;
    }
    __syncthreads();
    // park partials in rows 0..7 of pt (same swizzle discipline)
    smem[g * NPOS + (k ^ (g & 31))]            = S;
    smem[(4 + g) * NPOS + (k ^ ((4 + g) & 31))] = S2;
    __syncthreads();
    if (tid < 64) {
        float s = 0.f, s2 = 0.f;
#pragma unroll
        for (int g2 = 0; g2 < 4; ++g2) {
            s  += smem[g2 * NPOS + (tid ^ (g2 & 31))];
            s2 += smem[(4 + g2) * NPOS + (tid ^ ((4 + g2) & 31))];
        }
        part[((size_t)blockIdx.x * 2 + 0) * 64 + tid] = s;
        part[((size_t)blockIdx.x * 2 + 1) * 64 + tid] = s2;
    }
}

// ---------------- Kernel B: finalize per (b,z) ----------------
extern "C" __global__ void __launch_bounds__(256)
k_final(const float* __restrict__ x, const float* __restrict__ Wl,
        const float* __restrict__ part, float* __restrict__ out) {
    __shared__ float stg[STAGE_FLOATS];
    __shared__ float msh[NPOS], ish[NPOS];
    const int tid = threadIdx.x;
    const int b = blockIdx.x >> 3;   // 8 blocks per b

    const float4* s4 = (const float4*)(x + (size_t)blockIdx.x * STAGE_FLOATS);
    float4* l4 = (float4*)stg;
    for (int i = tid; i < STAGE_FLOATS / 4; i += 256) l4[i] = s4[i];

    // Fold the 8 z-chunk partials for this b -> mean / inv-std per position.
    if (tid < 64) {
        float s = 0.f, s2 = 0.f;
#pragma unroll
        for (int c = 0; c < 8; ++c) {
            const float* p = part + ((size_t)(b * 8 + c) * 2) * 64;
            s  += p[tid];
            s2 += p[64 + tid];
        }
        float m   = s * (1.f / 2048.f);
        float var = fmaf(-m, m, s2 * (1.f / 2048.f));
        msh[tid] = m;
        ish[tid] = var > 0.f ? rsqrtf(var) : 0.f;  // nan_to_num: degenerate -> 0
    }
    __syncthreads();

    float in[REC_LEN];
#pragma unroll
    for (int j = 0; j < REC_LEN; ++j) in[j] = stg[tid * REC_LEN + j];

    float v[NPOS];
    patchvals(in, v);

    // zscore over channels (broadcast LDS reads: k uniform across lanes -> free)
#pragma unroll
    for (int k = 0; k < NPOS; ++k)
        v[k] = (v[k] - msh[k]) * ish[k];

    const float w0 = Wl[0], w1 = Wl[1], w2 = Wl[2], w3 = Wl[3], w4 = Wl[4];
    float zz = 0.f, sp0 = 0.f, sp1 = 0.f, sp2 = 0.f, sp3 = 0.f;
#pragma unroll
    for (int n = 0; n < 16; ++n) {
        float a0 = v[n], a1 = v[16 + n], a2 = v[32 + n], a3 = v[48 + n];
        // zscore over the 4 pixels (stable form: deviations then sumsq)
        float m4 = 0.25f * (a0 + a1 + a2 + a3);
        float d0 = a0 - m4, d1 = a1 - m4, d2 = a2 - m4, d3 = a3 - m4;
        float var4 = 0.25f * (d0 * d0 + d1 * d1 + d2 * d2 + d3 * d3);
        float inv4 = var4 > 0.f ? rsqrtf(var4) : 0.f;   // nan_to_num
        float x0 = d0 * inv4, x1 = d1 * inv4, x2 = d2 * inv4, x3 = d3 * inv4;
        // ELM hidden (bias row first in Xb)
        float t = w0 + w1 * x0 + w2 * x1 + w3 * x2 + w4 * x3;
        float h = 1.f / (1.f + expf(-t));
        zz += h * h;
        sp0 += x0 * h; sp1 += x1 * h; sp2 += x2 * h; sp3 += x3 * h;
    }
    float izz = 1.f / zz;   // h>0 -> zz>0
    float b0 = sp0 * izz, b1 = sp1 * izz, b2 = sp2 * izz, b3 = sp3 * izz;
    float mb = 0.25f * (b0 + b1 + b2 + b3);
    float e0 = b0 - mb, e1 = b1 - mb, e2 = b2 - mb, e3 = b3 - mb;
    out[(size_t)blockIdx.x * 256 + tid] = sqrtf(0.25f * (e0 * e0 + e1 * e1 + e2 * e2 + e3 * e3));
}

extern "C" void kernel_launch(void* const* d_in, const int* in_sizes, int n_in,
                              void* d_out, int out_size, void* d_ws, size_t ws_size,
                              hipStream_t stream) {
    (void)in_sizes; (void)n_in; (void)out_size; (void)ws_size;
    const float* x  = (const float*)d_in[0];
    const float* Wl = (const float*)d_in[1];
    float* out  = (float*)d_out;
    float* part = (float*)d_ws;          // 2048 * 2 * 64 floats = 1 MB scratch

    k_stats<<<2048, 256, 0, stream>>>(x, part);
    k_final<<<2048, 256, 0, stream>>>(x, Wl, part, out);
}